// Round 2
// baseline (136.231 us; speedup 1.0000x reference)
//
#include <hip/hip_runtime.h>

#define CMID 256
#define CIN 3
#define DOUT 4096
#define LAMBDA 0.75f

// ---------------------------------------------------------------------------
// Kernel 0: zero the pooled accumulator (d_ws is poisoned 0xAA by harness)
// ---------------------------------------------------------------------------
__global__ void zero_pooled(float* __restrict__ pooled) {
    int i = blockIdx.x * blockDim.x + threadIdx.x;
    if (i < 32 * CMID) pooled[i] = 0.f;
}

// ---------------------------------------------------------------------------
// Kernel 1: fused conv3x3(pad=1) + bias + relu + hardshrink + partial pool.
// Block = (b, h): stages 3 channels x 3 rows x 130 cols of x into LDS.
// Thread t = output channel co; 27 weights live in VGPRs; x values are
// wave-uniform LDS broadcasts (conflict-free). 4-pixel unroll -> ds_read_b128.
// ---------------------------------------------------------------------------
__global__ __launch_bounds__(256) void conv_pool_kernel(
    const float* __restrict__ x, const float* __restrict__ conv_w,
    const float* __restrict__ conv_b, float* __restrict__ pooled)
{
    __shared__ float xs[3][3][132];   // [ci][row r=h-1..h+1][col j=-1..128], pad 132
    const int b = blockIdx.x >> 7;    // blockIdx.x / 128
    const int h = blockIdx.x & 127;
    const int t = threadIdx.x;        // co = t

    // ---- stage x into LDS (zero-padded borders) ----
    for (int i = t; i < 3 * 3 * 130; i += 256) {
        int ci  = i / 390;
        int rem = i - ci * 390;
        int r   = rem / 130;
        int j   = rem - r * 130;
        int hh  = h - 1 + r;
        int ww  = j - 1;
        float v = 0.f;
        if (hh >= 0 && hh < 128 && ww >= 0 && ww < 128)
            v = x[((b * 3 + ci) * 128 + hh) * 128 + ww];
        xs[ci][r][j] = v;
    }

    // ---- per-thread weights (co = t) ----
    float wreg[27];
    const float* wg = conv_w + t * 27;
    #pragma unroll
    for (int j = 0; j < 27; j++) wreg[j] = wg[j];
    const float bias = conv_b[t];

    __syncthreads();

    // ---- 128 output pixels of row h for channel t, 4-wide groups ----
    float bsum = 0.f;
    for (int w0 = 0; w0 < 128; w0 += 4) {
        float a0 = bias, a1 = bias, a2 = bias, a3 = bias;
        #pragma unroll
        for (int ci = 0; ci < 3; ci++) {
            #pragma unroll
            for (int r = 0; r < 3; r++) {
                const float* row = &xs[ci][r][w0];   // 16B-aligned (w0 % 4 == 0)
                float v0 = row[0], v1 = row[1], v2 = row[2];
                float v3 = row[3], v4 = row[4], v5 = row[5];
                const float k0 = wreg[(ci * 3 + r) * 3 + 0];
                const float k1 = wreg[(ci * 3 + r) * 3 + 1];
                const float k2 = wreg[(ci * 3 + r) * 3 + 2];
                a0 = fmaf(v0, k0, fmaf(v1, k1, fmaf(v2, k2, a0)));
                a1 = fmaf(v1, k0, fmaf(v2, k1, fmaf(v3, k2, a1)));
                a2 = fmaf(v2, k0, fmaf(v3, k1, fmaf(v4, k2, a2)));
                a3 = fmaf(v3, k0, fmaf(v4, k1, fmaf(v5, k2, a3)));
            }
        }
        // relu + hardshrink: post-relu y >= 0, keep iff y > 0.75
        bsum += (a0 > LAMBDA ? a0 : 0.f);
        bsum += (a1 > LAMBDA ? a1 : 0.f);
        bsum += (a2 > LAMBDA ? a2 : 0.f);
        bsum += (a3 > LAMBDA ? a3 : 0.f);
    }

    // partial pool over this h row; mean's /16384 applied in FC kernel
    atomicAdd(&pooled[b * CMID + t], bsum);
}

// ---------------------------------------------------------------------------
// Kernel 2: out[b][d] = log_sigmoid(dot(pooled[b]/16384, fc_w[d]) + fc_b[d])
// ---------------------------------------------------------------------------
__global__ __launch_bounds__(256) void fc_kernel(
    const float* __restrict__ pooled, const float* __restrict__ fc_w,
    const float* __restrict__ fc_b, float* __restrict__ out)
{
    __shared__ float pool[CMID];
    const int b = blockIdx.y;
    const int t = threadIdx.x;
    pool[t] = pooled[b * CMID + t] * (1.0f / 16384.0f);
    __syncthreads();

    const int d = blockIdx.x * 256 + t;
    const float4* wrow = (const float4*)(fc_w + d * CMID);  // 1KB-aligned rows
    float acc = fc_b[d];
    #pragma unroll 8
    for (int k4 = 0; k4 < CMID / 4; k4++) {
        float4 wv = wrow[k4];
        acc += wv.x * pool[k4 * 4 + 0] + wv.y * pool[k4 * 4 + 1]
             + wv.z * pool[k4 * 4 + 2] + wv.w * pool[k4 * 4 + 3];
    }
    // numerically stable log_sigmoid
    float ls = fminf(acc, 0.f) - log1pf(expf(-fabsf(acc)));
    out[b * (int)DOUT + d] = ls;
}

// ---------------------------------------------------------------------------
extern "C" void kernel_launch(void* const* d_in, const int* in_sizes, int n_in,
                              void* d_out, int out_size, void* d_ws, size_t ws_size,
                              hipStream_t stream) {
    const float* x      = (const float*)d_in[0];   // [32,3,128,128]
    const float* conv_w = (const float*)d_in[1];   // [256,3,3,3]
    const float* conv_b = (const float*)d_in[2];   // [256]
    const float* fc_w   = (const float*)d_in[3];   // [4096,256]
    const float* fc_b   = (const float*)d_in[4];   // [4096]
    float* out = (float*)d_out;                    // [32,4096]

    float* pooled = (float*)d_ws;                  // 32*256 floats = 32 KB

    zero_pooled<<<32, 256, 0, stream>>>(pooled);
    conv_pool_kernel<<<32 * 128, 256, 0, stream>>>(x, conv_w, conv_b, pooled);
    fc_kernel<<<dim3(16, 32), 256, 0, stream>>>(pooled, fc_w, fc_b, out);
}

// Round 3
// 127.466 us; speedup vs baseline: 1.0688x; 1.0688x over previous
//
#include <hip/hip_runtime.h>

#define CMID 256
#define DOUT 4096
#define LAMBDA 0.75f

// ---------------------------------------------------------------------------
// Kernel 0: zero the pooled accumulator
// ---------------------------------------------------------------------------
__global__ void zero_pooled(float* __restrict__ pooled) {
    int i = blockIdx.x * blockDim.x + threadIdx.x;
    if (i < 32 * CMID) pooled[i] = 0.f;
}

// ---------------------------------------------------------------------------
// Kernel 1: fused conv3x3(pad=1) + bias + relu + hardshrink + partial pool.
// Block = (b, row-pair h0,h0+1). Stages 3 ci x 4 rows x 136 cols into LDS
// (4-col pad front/back so 8-pixel group bases are 16B aligned).
// Thread t = output channel; 27 weights in VGPRs; LDS reads are wave-uniform
// broadcasts (conflict-free). Per (ci,r) per 8 outputs: 2x ds_read_b128 +
// 2 scalar border reads feed up to 48 FMAs.
// ---------------------------------------------------------------------------
__global__ __launch_bounds__(256) void conv_pool_kernel(
    const float* __restrict__ x, const float* __restrict__ conv_w,
    const float* __restrict__ conv_b, float* __restrict__ pooled)
{
    __shared__ float xs[3][4][136];   // [ci][staged row h0-1..h0+2][col j: col = j-4]
    const int b  = blockIdx.x >> 6;
    const int h0 = (blockIdx.x & 63) * 2;
    const int t  = threadIdx.x;       // co = t

    // ---- stage x into LDS (zero-padded borders) ----
    for (int i = t; i < 3 * 4 * 136; i += 256) {
        int ci  = i / 544;
        int rem = i - ci * 544;
        int r   = rem / 136;
        int j   = rem - r * 136;
        int hh  = h0 - 1 + r;
        int col = j - 4;
        float v = 0.f;
        if (hh >= 0 && hh < 128 && (unsigned)col < 128u)
            v = x[((b * 3 + ci) * 128 + hh) * 128 + col];
        xs[ci][r][j] = v;
    }

    // ---- per-thread weights (co = t) ----
    float wreg[27];
    const float* wg = conv_w + t * 27;
    #pragma unroll
    for (int j = 0; j < 27; j++) wreg[j] = wg[j];
    const float bias = conv_b[t];

    __syncthreads();

    // ---- 2 output rows x 128 px for channel t, 8-wide groups ----
    float bsum = 0.f;
    for (int g = 0; g < 16; ++g) {
        const int c0 = g * 8;
        float acc0[8], acc1[8];
        #pragma unroll
        for (int i = 0; i < 8; ++i) { acc0[i] = bias; acc1[i] = bias; }

        #pragma unroll
        for (int ci = 0; ci < 3; ++ci) {
            #pragma unroll
            for (int r = 0; r < 4; ++r) {
                const float* row = &xs[ci][r][c0 + 4];   // 16B aligned
                float v[10];                              // cols c0-1 .. c0+8
                v[0] = row[-1];
                float4 a4 = *(const float4*)(row);
                float4 b4 = *(const float4*)(row + 4);
                v[1] = a4.x; v[2] = a4.y; v[3] = a4.z; v[4] = a4.w;
                v[5] = b4.x; v[6] = b4.y; v[7] = b4.z; v[8] = b4.w;
                v[9] = row[8];
                if (r <= 2) {   // contributes to output row h0 with ky = r
                    const float k0 = wreg[ci * 9 + r * 3 + 0];
                    const float k1 = wreg[ci * 9 + r * 3 + 1];
                    const float k2 = wreg[ci * 9 + r * 3 + 2];
                    #pragma unroll
                    for (int i = 0; i < 8; ++i)
                        acc0[i] = fmaf(v[i], k0, fmaf(v[i+1], k1, fmaf(v[i+2], k2, acc0[i])));
                }
                if (r >= 1) {   // contributes to output row h0+1 with ky = r-1
                    const float k0 = wreg[ci * 9 + (r-1) * 3 + 0];
                    const float k1 = wreg[ci * 9 + (r-1) * 3 + 1];
                    const float k2 = wreg[ci * 9 + (r-1) * 3 + 2];
                    #pragma unroll
                    for (int i = 0; i < 8; ++i)
                        acc1[i] = fmaf(v[i], k0, fmaf(v[i+1], k1, fmaf(v[i+2], k2, acc1[i])));
                }
            }
        }

        // relu + hardshrink (post-relu y >= 0: keep iff y > 0.75)
        #pragma unroll
        for (int i = 0; i < 8; ++i) {
            bsum += (acc0[i] > LAMBDA ? acc0[i] : 0.f);
            bsum += (acc1[i] > LAMBDA ? acc1[i] : 0.f);
        }
    }

    // partial pool over 2 rows; mean's /16384 applied in FC kernel
    atomicAdd(&pooled[b * CMID + t], bsum);
}

// ---------------------------------------------------------------------------
// Kernel 2: out[b][d] = log_sigmoid(dot(pooled[b]/16384, fc_w[d]) + fc_b[d])
// ---------------------------------------------------------------------------
__global__ __launch_bounds__(256) void fc_kernel(
    const float* __restrict__ pooled, const float* __restrict__ fc_w,
    const float* __restrict__ fc_b, float* __restrict__ out)
{
    __shared__ float pool[CMID];
    const int b = blockIdx.y;
    const int t = threadIdx.x;
    pool[t] = pooled[b * CMID + t] * (1.0f / 16384.0f);
    __syncthreads();

    const int d = blockIdx.x * 256 + t;
    const float4* wrow = (const float4*)(fc_w + d * CMID);
    float acc = fc_b[d];
    #pragma unroll 8
    for (int k4 = 0; k4 < CMID / 4; k4++) {
        float4 wv = wrow[k4];
        acc += wv.x * pool[k4 * 4 + 0] + wv.y * pool[k4 * 4 + 1]
             + wv.z * pool[k4 * 4 + 2] + wv.w * pool[k4 * 4 + 3];
    }
    float ls = fminf(acc, 0.f) - log1pf(expf(-fabsf(acc)));
    out[b * (int)DOUT + d] = ls;
}

// ---------------------------------------------------------------------------
extern "C" void kernel_launch(void* const* d_in, const int* in_sizes, int n_in,
                              void* d_out, int out_size, void* d_ws, size_t ws_size,
                              hipStream_t stream) {
    const float* x      = (const float*)d_in[0];   // [32,3,128,128]
    const float* conv_w = (const float*)d_in[1];   // [256,3,3,3]
    const float* conv_b = (const float*)d_in[2];   // [256]
    const float* fc_w   = (const float*)d_in[3];   // [4096,256]
    const float* fc_b   = (const float*)d_in[4];   // [4096]
    float* out = (float*)d_out;                    // [32,4096]

    float* pooled = (float*)d_ws;                  // 32*256 floats = 32 KB

    zero_pooled<<<32, 256, 0, stream>>>(pooled);
    conv_pool_kernel<<<32 * 64, 256, 0, stream>>>(x, conv_w, conv_b, pooled);
    fc_kernel<<<dim3(16, 32), 256, 0, stream>>>(pooled, fc_w, fc_b, out);
}

// Round 4
// 49.496 us; speedup vs baseline: 2.7523x; 2.5753x over previous
//
#include <hip/hip_runtime.h>
#include <hip/hip_bf16.h>

#define LAMBDA 0.75f
#define CMID 256
#define DOUT 4096

typedef __attribute__((ext_vector_type(8))) short bf16x8;   // 8 bf16 = 4 VGPR
typedef __attribute__((ext_vector_type(4))) float f32x4;    // MFMA C/D

static inline __device__ short f2bf(float f) {
    __hip_bfloat16 h = __float2bfloat16(f);
    short s;
    __builtin_memcpy(&s, &h, 2);
    return s;
}

// ---------------------------------------------------------------------------
__global__ void zero_pooled(float* __restrict__ pooled) {
    int i = blockIdx.x * blockDim.x + threadIdx.x;
    if (i < 32 * CMID) pooled[i] = 0.f;
}

// ---------------------------------------------------------------------------
// Implicit-GEMM conv3x3 via MFMA + fused bias/relu/hardshrink/pool.
// Block = (b, 4 output rows). 4 waves; wave w owns co [64w,64w+64) (4 co-tiles).
// K=27 padded to 32; k-slot (g=lane>>4, j=0..7):
//   g<3 : ci=g, tap j (ky=j/3,kx=j%3)        [taps 0..7]
//   g==3: j<3 -> ci=j, tap 8 (ky=2,kx=2); j>=3 -> zero-weight pad
// Same (g,j) assignment on A and B => correct for ANY HW k=sigma(g,j) bijection.
// ---------------------------------------------------------------------------
__global__ __launch_bounds__(256) void conv_pool_mfma(
    const float* __restrict__ x, const float* __restrict__ conv_w,
    const float* __restrict__ conv_b, float* __restrict__ pooled)
{
    __shared__ float xs[3 * 6 * 132];  // [ci][rows h0-1..h0+4][cols -1..130], zero-padded
    const int b  = blockIdx.x >> 5;
    const int h0 = (blockIdx.x & 31) * 4;
    const int t  = threadIdx.x;
    const int wv = t >> 6;        // wave id 0..3
    const int l  = t & 63;
    const int lm = l & 15;        // A row (co) / B col (px) index
    const int g  = l >> 4;        // k-slot group

    // ---- stage x rows h0-1..h0+4 into LDS, borders zeroed ----
    for (int i = t; i < 2376; i += 256) {
        int ci  = i / 792;
        int rem = i - ci * 792;
        int r   = rem / 132;
        int j   = rem - r * 132;
        int hh  = h0 - 1 + r;
        int col = j - 1;
        float v = 0.f;
        if ((unsigned)hh < 128u && (unsigned)col < 128u)
            v = x[(b * 3 + ci) * 16384 + hh * 128 + col];
        xs[i] = v;
    }

    // ---- A-frags (weights, bf16) + bias C-in frags for 4 co-tiles ----
    bf16x8 afrag[4];
    f32x4  biasf[4];
    f32x4  pool[4];
    #pragma unroll
    for (int c = 0; c < 4; ++c) {
        const int ct = wv * 4 + c;
        const int co = ct * 16 + lm;
        const float* wp = conv_w + co * 27;
        float av[8];
        if (g < 3) {
            #pragma unroll
            for (int j = 0; j < 8; ++j) av[j] = wp[g * 9 + j];
        } else {
            av[0] = wp[8]; av[1] = wp[17]; av[2] = wp[26];
            av[3] = av[4] = av[5] = av[6] = av[7] = 0.f;
        }
        #pragma unroll
        for (int j = 0; j < 8; ++j) afrag[c][j] = f2bf(av[j]);
        #pragma unroll
        for (int r = 0; r < 4; ++r) {
            biasf[c][r] = conv_b[ct * 16 + 4 * g + r];  // C/D row = 4*(l>>4)+r
            pool[c][r]  = 0.f;
        }
    }

    // ---- per-lane B-gather offsets (elements, relative to xs[rr*132+1+lm]) ----
    int off[8];
    if (g < 3) {
        #pragma unroll
        for (int j = 0; j < 8; ++j)
            off[j] = g * 792 + (j / 3) * 132 + (j % 3) - 1;
    } else {
        off[0] = 0 * 792 + 2 * 132 + 1;
        off[1] = 1 * 792 + 2 * 132 + 1;
        off[2] = 2 * 792 + 2 * 132 + 1;
        off[3] = off[4] = off[5] = off[6] = off[7] = 0;  // dead: A-weight is 0
    }

    __syncthreads();

    // ---- main loop: 4 rows x 8 px-tiles of 16 ----
    #pragma unroll
    for (int rr = 0; rr < 4; ++rr) {
        const float* base = xs + rr * 132 + 1 + lm;
        #pragma unroll
        for (int tw = 0; tw < 8; ++tw) {
            float v[8];
            #pragma unroll
            for (int j = 0; j < 8; ++j) v[j] = base[off[j] + tw * 16];
            bf16x8 bfrag;
            #pragma unroll
            for (int j = 0; j < 8; ++j) bfrag[j] = f2bf(v[j]);
            #pragma unroll
            for (int c = 0; c < 4; ++c) {
                f32x4 acc = __builtin_amdgcn_mfma_f32_16x16x32_bf16(
                    afrag[c], bfrag, biasf[c], 0, 0, 0);
                #pragma unroll
                for (int r = 0; r < 4; ++r)
                    pool[c][r] += (acc[r] > LAMBDA) ? acc[r] : 0.f;  // relu+hardshrink
            }
        }
    }

    // ---- reduce over the 16 px lanes, then atomicAdd into pooled ----
    #pragma unroll
    for (int m = 1; m < 16; m <<= 1) {
        #pragma unroll
        for (int c = 0; c < 4; ++c)
            #pragma unroll
            for (int r = 0; r < 4; ++r)
                pool[c][r] += __shfl_xor(pool[c][r], m, 64);
    }
    if (lm == 0) {
        #pragma unroll
        for (int c = 0; c < 4; ++c)
            #pragma unroll
            for (int r = 0; r < 4; ++r)
                atomicAdd(&pooled[b * CMID + (wv * 4 + c) * 16 + 4 * g + r], pool[c][r]);
    }
}

// ---------------------------------------------------------------------------
// FC: out[b][d] = log_sigmoid(dot(pooled[b]/16384, fc_w[d]) + fc_b[d])
// ---------------------------------------------------------------------------
__global__ __launch_bounds__(256) void fc_kernel(
    const float* __restrict__ pooled, const float* __restrict__ fc_w,
    const float* __restrict__ fc_b, float* __restrict__ out)
{
    __shared__ float pool[CMID];
    const int b = blockIdx.y;
    const int t = threadIdx.x;
    pool[t] = pooled[b * CMID + t] * (1.0f / 16384.0f);
    __syncthreads();

    const int d = blockIdx.x * 256 + t;
    const float4* wrow = (const float4*)(fc_w + d * CMID);
    float acc = fc_b[d];
    #pragma unroll 8
    for (int k4 = 0; k4 < CMID / 4; k4++) {
        float4 wv = wrow[k4];
        acc += wv.x * pool[k4 * 4 + 0] + wv.y * pool[k4 * 4 + 1]
             + wv.z * pool[k4 * 4 + 2] + wv.w * pool[k4 * 4 + 3];
    }
    float ls = fminf(acc, 0.f) - log1pf(expf(-fabsf(acc)));
    out[b * (int)DOUT + d] = ls;
}

// ---------------------------------------------------------------------------
extern "C" void kernel_launch(void* const* d_in, const int* in_sizes, int n_in,
                              void* d_out, int out_size, void* d_ws, size_t ws_size,
                              hipStream_t stream) {
    const float* x      = (const float*)d_in[0];   // [32,3,128,128]
    const float* conv_w = (const float*)d_in[1];   // [256,3,3,3]
    const float* conv_b = (const float*)d_in[2];   // [256]
    const float* fc_w   = (const float*)d_in[3];   // [4096,256]
    const float* fc_b   = (const float*)d_in[4];   // [4096]
    float* out = (float*)d_out;                    // [32,4096]

    float* pooled = (float*)d_ws;                  // 32*256 floats

    zero_pooled<<<32, 256, 0, stream>>>(pooled);
    conv_pool_mfma<<<32 * 32, 256, 0, stream>>>(x, conv_w, conv_b, pooled);
    fc_kernel<<<dim3(16, 32), 256, 0, stream>>>(pooled, fc_w, fc_b, out);
}